// Round 2
// baseline (399.527 us; speedup 1.0000x reference)
//
#include <hip/hip_runtime.h>

// Problem constants
constexpr int D0  = 11;
constexpr int Hh  = 200;
constexpr int Ww  = 176;
constexpr int HWC = Hh * Ww;        // 35200
constexpr int NV  = 16000;
constexpr int CIN = 128;
constexpr int ND1 = 5;              // D after first stride-2 (VALID, k=3)
constexpr int ND2 = 2;
constexpr int MAXN1 = 32000;        // each voxel maps to <=2 level-1 slices
constexpr float EPS = 1e-5f;

// ---------------- setup kernels ----------------

__global__ __launch_bounds__(256) void scatter_k(const int* __restrict__ coors,
                                                 int* __restrict__ grid0) {
    int i = blockIdx.x * blockDim.x + threadIdx.x;
    if (i >= NV) return;
    const int4 c = reinterpret_cast<const int4*>(coors)[i];   // b,z,y,x
    grid0[c.y * HWC + c.z * Ww + c.w] = i;
}

// w[o][i][k] -> wt[k][i][o]   (O always 64)
__global__ __launch_bounds__(256) void transpose_all_k(
    const float* __restrict__ w1, const float* __restrict__ w2,
    const float* __restrict__ w3, const float* __restrict__ w4,
    const float* __restrict__ w5,
    float* __restrict__ w1t, float* __restrict__ w2t, float* __restrict__ w3t,
    float* __restrict__ w4t, float* __restrict__ w5t) {
    const float* src; float* dst; int I, K;
    switch (blockIdx.y) {
        case 0: src = w1; dst = w1t; I = 128; K = 27; break;
        case 1: src = w2; dst = w2t; I = 64;  K = 3;  break;
        case 2: src = w3; dst = w3t; I = 64;  K = 27; break;
        case 3: src = w4; dst = w4t; I = 64;  K = 27; break;
        default: src = w5; dst = w5t; I = 64; K = 3;  break;
    }
    int tot = 64 * I * K;
    int idx = blockIdx.x * blockDim.x + threadIdx.x;
    if (idx >= tot) return;
    int o = idx / (I * K);
    int r = idx % (I * K);
    int ii = r / K;
    int k  = r % K;
    dst[(k * I + ii) * 64 + o] = src[idx];
}

__global__ __launch_bounds__(256) void build_l1_k(const int* __restrict__ grid0,
                                                  int* __restrict__ grid1,
                                                  int* __restrict__ list1,
                                                  int* __restrict__ cnt) {
    int p = blockIdx.x * blockDim.x + threadIdx.x;
    if (p >= ND1 * HWC) return;
    int d1 = p / HWC, yx = p % HWC;
    int base = (2 * d1) * HWC + yx;
    bool occ = (grid0[base] >= 0) | (grid0[base + HWC] >= 0) | (grid0[base + 2 * HWC] >= 0);
    if (occ) {
        int s = atomicAdd(cnt, 1);
        grid1[p] = s;
        list1[s] = p;
    }
}

// ---------------- batched sparse conv ----------------
// One wave per CHUNK of sites. lane = output channel (64).
// Per tap: weights for the tap staged into VGPRs (wreg[CC]), then swept
// over the chunk's occupied sites; activations read via wave-uniform
// (scalar) loads. Tap-splitting across blockIdx.y (KG taps per group)
// writes raw partial sums; combine_k applies BN+ReLU.
// MODE: 0=conv1 (grid0, 3x3x3, coors sites), 1=conv2 (grid0, 3x1x1 s2),
//       2=conv3/4 (grid1, 3x3x3, list1 sites), 3=conv5 (grid1 dense out, 3x1x1 s2)

template<int CC, int CHUNK, int NT, int KG, int MODE, bool SPLIT>
__global__ __launch_bounds__(64) void convb_k(
    const float* __restrict__ fin, const float* __restrict__ wtab,
    const int* __restrict__ g0, const int* __restrict__ g1,
    const int* __restrict__ list1, const int* __restrict__ cnt,
    const int* __restrict__ coors,
    const float* __restrict__ bg, const float* __restrict__ bb,
    const float* __restrict__ bm, const float* __restrict__ bv,
    float* __restrict__ fout,
    float* __restrict__ p0, float* __restrict__ p1, float* __restrict__ p2) {

    __shared__ int jrow[KG * CHUNK];
    const int lane = threadIdx.x;
    const int base = blockIdx.x * CHUNK;
    const int ts = SPLIT ? blockIdx.y * KG : 0;

    int limit;
    if constexpr (MODE == 0)      limit = NV;
    else if constexpr (MODE == 3) limit = ND2 * HWC;
    else                          limit = cnt[0];

    // ---- Phase A: gather neighbor ids for this chunk's sites (lane = site)
    if (lane < CHUNK) {
        const int site = base + lane;
        const bool valid = site < limit;
        if constexpr (MODE == 0) {
            int4 c = make_int4(0, 0, 0, 0);
            if (valid) c = reinterpret_cast<const int4*>(coors)[site];
            #pragma unroll
            for (int kk = 0; kk < KG; ++kk) {
                int k = ts + kk;
                int kd = k / 9, r = k % 9, kh = r / 3, kw = r % 3;
                int zz = c.y + kd - 1, yy = c.z + kh - 1, xx = c.w + kw - 1;
                int j = -1;
                if (valid && (unsigned)zz < (unsigned)D0 && (unsigned)yy < (unsigned)Hh &&
                    (unsigned)xx < (unsigned)Ww)
                    j = g0[zz * HWC + yy * Ww + xx];
                jrow[kk * CHUNK + lane] = j;
            }
        } else if constexpr (MODE == 1) {
            int p = 0; if (valid) p = list1[site];
            int d1 = p / HWC, yx = p % HWC;
            #pragma unroll
            for (int kk = 0; kk < KG; ++kk)
                jrow[kk * CHUNK + lane] = valid ? g0[(2 * d1 + ts + kk) * HWC + yx] : -1;
        } else if constexpr (MODE == 2) {
            int p = 0; if (valid) p = list1[site];
            int d1 = p / HWC, yx = p % HWC, y = yx / Ww, x = yx % Ww;
            #pragma unroll
            for (int kk = 0; kk < KG; ++kk) {
                int k = ts + kk;
                int kd = k / 9, r = k % 9, kh = r / 3, kw = r % 3;
                int dd = d1 + kd - 1, yy = y + kh - 1, xx = x + kw - 1;
                int j = -1;
                if (valid && (unsigned)dd < (unsigned)ND1 && (unsigned)yy < (unsigned)Hh &&
                    (unsigned)xx < (unsigned)Ww)
                    j = g1[dd * HWC + yy * Ww + xx];
                jrow[kk * CHUNK + lane] = j;
            }
        } else {
            int d2 = (base + lane) / HWC, yx = (base + lane) % HWC;
            #pragma unroll
            for (int kk = 0; kk < KG; ++kk)
                jrow[kk * CHUNK + lane] = valid ? g1[(2 * d2 + kk) * HWC + yx] : -1;
        }
    }
    __syncthreads();

    // ---- Phase B: lane = output channel; sweep taps, then chunk sites
    const int o = lane;
    float acc[CHUNK];
    #pragma unroll
    for (int s = 0; s < CHUNK; ++s) acc[s] = 0.f;

    #pragma unroll 1
    for (int kk = 0; kk < KG; ++kk) {
        int jv = jrow[kk * CHUNK + (lane & (CHUNK - 1))];
        unsigned long long bal = __ballot(jv >= 0);
        unsigned mk = (unsigned)(bal & ((1ull << CHUNK) - 1));
        if (mk == 0) continue;

        // stage this tap's weight column into VGPRs (coalesced: [cc][o] layout)
        float wreg[CC];
        const float* wp = wtab + (size_t)(ts + kk) * (CC * 64) + o;
        #pragma unroll
        for (int cc = 0; cc < CC; ++cc) wreg[cc] = wp[cc * 64];

        #pragma unroll
        for (int s = 0; s < CHUNK; ++s) {
            if (mk & (1u << s)) {
                int j = __builtin_amdgcn_readfirstlane(jrow[kk * CHUNK + s]);
                const float* xp = fin + (size_t)j * CC;   // wave-uniform -> scalar loads
                float a0 = 0.f, a1 = 0.f, a2 = 0.f, a3 = 0.f;
                #pragma unroll
                for (int cc = 0; cc < CC; cc += 4) {
                    a0 = fmaf(xp[cc],     wreg[cc],     a0);
                    a1 = fmaf(xp[cc + 1], wreg[cc + 1], a1);
                    a2 = fmaf(xp[cc + 2], wreg[cc + 2], a2);
                    a3 = fmaf(xp[cc + 3], wreg[cc + 3], a3);
                }
                acc[s] += (a0 + a1) + (a2 + a3);
            }
        }
    }

    // ---- Phase C: store
    if constexpr (SPLIT) {
        float* pout = (blockIdx.y == 0) ? p0 : (blockIdx.y == 1) ? p1 : p2;
        #pragma unroll
        for (int s = 0; s < CHUNK; ++s) {
            int site = base + s;
            if (site < limit) pout[(size_t)site * 64 + o] = acc[s];
        }
    } else {
        float g = bg[o];
        float sc = g / sqrtf(bv[o] + EPS);
        float sh = bb[o] - bm[o] * sc;
        #pragma unroll
        for (int s = 0; s < CHUNK; ++s) {
            int site = base + s;
            if (site < limit) {
                float v = fmaxf(fmaf(acc[s], sc, sh), 0.f);
                if constexpr (MODE == 3) {
                    bool any = false;
                    #pragma unroll
                    for (int kk = 0; kk < KG; ++kk) any |= (jrow[kk * CHUNK + s] >= 0);
                    if (any) {
                        int d2 = site / HWC, yx = site % HWC;
                        fout[(size_t)(o * ND2 + d2) * HWC + yx] = v;
                    }
                } else {
                    fout[(size_t)site * 64 + o] = v;
                }
            }
        }
    }
}

// sum 3 partials + BN + ReLU
template<int MODE>   // 0: limit=NV, else limit=cnt[0]
__global__ __launch_bounds__(256) void combine_k(
    const float* __restrict__ p0, const float* __restrict__ p1,
    const float* __restrict__ p2, const int* __restrict__ cnt,
    const float* __restrict__ bg, const float* __restrict__ bb,
    const float* __restrict__ bm, const float* __restrict__ bv,
    float* __restrict__ fout) {
    int limit = (MODE == 0) ? NV : cnt[0];
    int idx = blockIdx.x * 256 + threadIdx.x;
    int site = idx >> 6, o = idx & 63;
    if (site >= limit) return;
    size_t off = (size_t)site * 64 + o;
    float v = p0[off] + p1[off] + p2[off];
    float g = bg[o];
    float sc = g / sqrtf(bv[o] + EPS);
    float sh = bb[o] - bm[o] * sc;
    fout[off] = fmaxf(fmaf(v, sc, sh), 0.f);
}

// ---------------- launch ----------------

extern "C" void kernel_launch(void* const* d_in, const int* in_sizes, int n_in,
                              void* d_out, int out_size, void* d_ws, size_t ws_size,
                              hipStream_t stream) {
    const float* vf = (const float*)d_in[0];
    const float* w1 = (const float*)d_in[1];
    const float* w2 = (const float*)d_in[2];
    const float* w3 = (const float*)d_in[3];
    const float* w4 = (const float*)d_in[4];
    const float* w5 = (const float*)d_in[5];
    const float* bg = (const float*)d_in[6];
    const float* bb = (const float*)d_in[7];
    const float* bm = (const float*)d_in[8];
    const float* bv = (const float*)d_in[9];
    const int* coors = (const int*)d_in[10];
    float* out = (float*)d_out;

    char* ws = (char*)d_ws;
    size_t off = 0;
    auto take = [&](size_t n) -> void* {
        void* pp = ws + off;
        off += (n + 255) & ~(size_t)255;
        return pp;
    };
    int*   grid0 = (int*)take((size_t)D0 * HWC * 4);
    int*   grid1 = (int*)take((size_t)ND1 * HWC * 4);
    int*   list1 = (int*)take(MAXN1 * 4);
    int*   cnt   = (int*)take(256);
    float* w1t   = (float*)take((size_t)27 * CIN * 64 * 4);
    float* w2t   = (float*)take((size_t)3 * 64 * 64 * 4);
    float* w3t   = (float*)take((size_t)27 * 64 * 64 * 4);
    float* w4t   = (float*)take((size_t)27 * 64 * 64 * 4);
    float* w5t   = (float*)take((size_t)3 * 64 * 64 * 4);
    const size_t FSZ = (size_t)MAXN1 * 64 * 4;   // 8.19 MB
    float* fA = (float*)take(FSZ);
    float* fB = (float*)take(FSZ);
    float* fC = (float*)take(FSZ);
    float* fD = (float*)take(FSZ);

    hipMemsetAsync(grid0, 0xFF, (size_t)D0 * HWC * 4, stream);   // -1
    hipMemsetAsync(grid1, 0xFF, (size_t)ND1 * HWC * 4, stream);  // -1
    hipMemsetAsync(cnt, 0, 256, stream);
    hipMemsetAsync(out, 0, (size_t)out_size * 4, stream);

    scatter_k<<<(NV + 255) / 256, 256, 0, stream>>>(coors, grid0);

    dim3 tg((27 * CIN * 64 + 255) / 256, 5);
    transpose_all_k<<<tg, 256, 0, stream>>>(w1, w2, w3, w4, w5, w1t, w2t, w3t, w4t, w5t);

    build_l1_k<<<(ND1 * HWC + 255) / 256, 256, 0, stream>>>(grid0, grid1, list1, cnt);

    // conv1: 128->64, 27 taps, tap-split x3, chunk 16  (partials B,C,D -> A)
    convb_k<128, 16, 27, 9, 0, true><<<dim3(NV / 16, 3), 64, 0, stream>>>(
        vf, w1t, grid0, grid1, list1, cnt, coors,
        bg, bb, bm, bv, nullptr, fB, fC, fD);
    combine_k<0><<<(NV * 64) / 256, 256, 0, stream>>>(
        fB, fC, fD, cnt, bg, bb, bm, bv, fA);

    // conv2: 64->64, 3 taps (D-stride 2), chunk 16, no split  (A -> B)
    convb_k<64, 16, 3, 3, 1, false><<<dim3(MAXN1 / 16, 1), 64, 0, stream>>>(
        fA, w2t, grid0, grid1, list1, cnt, coors,
        bg + 64, bb + 64, bm + 64, bv + 64, fB, nullptr, nullptr, nullptr);

    // conv3: 64->64, 27 taps, split x3, chunk 32  (B -> partials A,C,D -> B)
    convb_k<64, 32, 27, 9, 2, true><<<dim3(MAXN1 / 32, 3), 64, 0, stream>>>(
        fB, w3t, grid0, grid1, list1, cnt, coors,
        bg + 128, bb + 128, bm + 128, bv + 128, nullptr, fA, fC, fD);
    combine_k<2><<<(MAXN1 * 64) / 256, 256, 0, stream>>>(
        fA, fC, fD, cnt, bg + 128, bb + 128, bm + 128, bv + 128, fB);

    // conv4: same shape as conv3  (B -> partials A,C,D -> B)
    convb_k<64, 32, 27, 9, 2, true><<<dim3(MAXN1 / 32, 3), 64, 0, stream>>>(
        fB, w4t, grid0, grid1, list1, cnt, coors,
        bg + 192, bb + 192, bm + 192, bv + 192, nullptr, fA, fC, fD);
    combine_k<2><<<(MAXN1 * 64) / 256, 256, 0, stream>>>(
        fA, fC, fD, cnt, bg + 192, bb + 192, bm + 192, bv + 192, fB);

    // conv5: 64->64, 3 taps (D-stride 2), dense level-2 output, masked store
    convb_k<64, 32, 3, 3, 3, false><<<dim3((ND2 * HWC + 31) / 32, 1), 64, 0, stream>>>(
        fB, w5t, grid0, grid1, list1, cnt, coors,
        bg + 256, bb + 256, bm + 256, bv + 256, out, nullptr, nullptr, nullptr);
}